// Round 2
// baseline (1508.122 us; speedup 1.0000x reference)
//
#include <hip/hip_runtime.h>
#include <math.h>

#define N_NODES 100000
#define NE 1000000
#define D_NODE 64
#define D_EDGE 32
#define HID 64
#define H2C 32
#define D_IN 160  // 2*D_NODE + D_EDGE

// d_ws layout (in doubles):
#define OFF_W1 0        // 64*160 = 10240
#define OFF_B1 10240    // 64
#define OFF_W2 10304    // 32*64 = 2048
#define OFF_B2 12352    // 32
#define OFF_W3 12384    // 32
#define OFF_B3 12416    // 1
#define WS_DOUBLES 12417
#define WS_NEED_BYTES (WS_DOUBLES * 8)

// Pre-convert all weights/biases to f64 in workspace (runs every call;
// deterministic).
__global__ void prep_weights_kernel(const float* __restrict__ W1, const float* __restrict__ b1,
                                    const float* __restrict__ W2, const float* __restrict__ b2,
                                    const float* __restrict__ W3, const float* __restrict__ b3,
                                    double* __restrict__ ws)
{
    const int t = blockIdx.x * blockDim.x + threadIdx.x;
    const int stride = gridDim.x * blockDim.x;
    for (int i = t; i < HID * D_IN; i += stride) ws[OFF_W1 + i] = (double)W1[i];
    for (int i = t; i < HID; i += stride)        ws[OFF_B1 + i] = (double)b1[i];
    for (int i = t; i < H2C * HID; i += stride)  ws[OFF_W2 + i] = (double)W2[i];
    for (int i = t; i < H2C; i += stride)        ws[OFF_B2 + i] = (double)b2[i];
    for (int i = t; i < H2C; i += stride)        ws[OFF_W3 + i] = (double)W3[i];
    if (t == 0) ws[OFF_B3] = (double)b3[0];
}

// USE_WS=true: weights come pre-converted (f64) from ws via uniform scalar
// loads. USE_WS=false (fallback if ws too small): convert f32 weights inline.
template <bool USE_WS>
__global__ __launch_bounds__(256) void edge_mlp_f64_kernel(
    const float* __restrict__ nf,   // [N_NODES][D_NODE]
    const int*   __restrict__ ei,   // [2][E] int32 or int64-as-dwords
    const float* __restrict__ ef,   // [E][D_EDGE]
    const float* __restrict__ W1f, const float* __restrict__ b1f,
    const float* __restrict__ W2f, const float* __restrict__ b2f,
    const float* __restrict__ W3f, const float* __restrict__ b3f,
    const double* __restrict__ ws,
    float* __restrict__ out)        // [2E]: scores then mask
{
    const int e = blockIdx.x * blockDim.x + threadIdx.x;
    if (e >= NE) return;

    // int64 detection: odd dwords of small int64 values are 0. Uniform branch.
    const int is64 = (ei[1] == 0) & (ei[3] == 0) & (ei[5] == 0) & (ei[7] == 0);
    int si, ti;
    if (is64) {
        si = ei[2 * (size_t)e];
        ti = ei[2 * ((size_t)NE + e)];
    } else {
        si = ei[e];
        ti = ei[NE + e];
    }

    const float* __restrict__ srcp = nf + (size_t)si * D_NODE;
    const float* __restrict__ tgtp = nf + (size_t)ti * D_NODE;
    const float* __restrict__ efp  = ef + (size_t)e  * D_EDGE;

    const double* __restrict__ dW1 = ws + OFF_W1;
    const double* __restrict__ db1 = ws + OFF_B1;
    const double* __restrict__ dW2 = ws + OFF_W2;
    const double* __restrict__ db2 = ws + OFF_B2;
    const double* __restrict__ dW3 = ws + OFF_W3;

    // ---- Layer 1 (f64): acc[j] = b1[j] + sum_k combined[k]*W1[j][k] ----
    double acc[HID];
    #pragma unroll
    for (int j = 0; j < HID; ++j)
        acc[j] = USE_WS ? db1[j] : (double)b1f[j];

    #pragma unroll 1
    for (int kc = 0; kc < D_IN / 16; ++kc) {
        const float* base = (kc < 4) ? (srcp + kc * 16)
                          : (kc < 8) ? (tgtp + (kc - 4) * 16)
                                     : (efp  + (kc - 8) * 16);
        double cd[16];
        #pragma unroll
        for (int q = 0; q < 4; ++q) {
            const float4 v = *reinterpret_cast<const float4*>(base + q * 4);
            cd[q * 4 + 0] = (double)v.x; cd[q * 4 + 1] = (double)v.y;
            cd[q * 4 + 2] = (double)v.z; cd[q * 4 + 3] = (double)v.w;
        }
        #pragma unroll
        for (int j = 0; j < HID; ++j) {
            #pragma unroll
            for (int q = 0; q < 16; ++q) {
                const int wi = j * D_IN + kc * 16 + q;  // uniform index
                const double w = USE_WS ? dW1[wi] : (double)W1f[wi];
                acc[j] = fma(cd[q], w, acc[j]);
            }
        }
    }
    #pragma unroll
    for (int j = 0; j < HID; ++j) acc[j] = fmax(acc[j], 0.0);

    // ---- Layers 2+3 fused (f64) ----
    double logit = USE_WS ? ws[OFF_B3] : (double)b3f[0];
    #pragma unroll 1
    for (int jj = 0; jj < H2C; ++jj) {
        double h = USE_WS ? db2[jj] : (double)b2f[jj];
        #pragma unroll
        for (int j = 0; j < HID; ++j) {
            const int wi = jj * HID + j;  // uniform index
            const double w = USE_WS ? dW2[wi] : (double)W2f[wi];
            h = fma(acc[j], w, h);
        }
        h = fmax(h, 0.0);
        const double w3 = USE_WS ? dW3[jj] : (double)W3f[jj];
        logit = fma(h, w3, logit);
    }

    const double score_d = 1.0 / (1.0 + exp(-logit));
    const float  score_f = (float)score_d;
    out[e] = score_f;
    out[(size_t)NE + e] = (score_f >= 0.5f) ? 1.0f : 0.0f;
}

extern "C" void kernel_launch(void* const* d_in, const int* in_sizes, int n_in,
                              void* d_out, int out_size, void* d_ws, size_t ws_size,
                              hipStream_t stream) {
    const float* nf = (const float*)d_in[0];
    const int*   ei = (const int*)  d_in[1];
    const float* ef = (const float*)d_in[2];
    const float* W1 = (const float*)d_in[3];
    const float* b1 = (const float*)d_in[4];
    const float* W2 = (const float*)d_in[5];
    const float* b2 = (const float*)d_in[6];
    const float* W3 = (const float*)d_in[7];
    const float* b3 = (const float*)d_in[8];
    float* out = (float*)d_out;
    double* ws = (double*)d_ws;

    const int block = 256;
    const int grid = (NE + block - 1) / block;

    if (ws_size >= (size_t)WS_NEED_BYTES) {
        hipLaunchKernelGGL(prep_weights_kernel, dim3(48), dim3(256), 0, stream,
                           W1, b1, W2, b2, W3, b3, ws);
        hipLaunchKernelGGL((edge_mlp_f64_kernel<true>), dim3(grid), dim3(block), 0, stream,
                           nf, ei, ef, W1, b1, W2, b2, W3, b3, ws, out);
    } else {
        hipLaunchKernelGGL((edge_mlp_f64_kernel<false>), dim3(grid), dim3(block), 0, stream,
                           nf, ei, ef, W1, b1, W2, b2, W3, b3, ws, out);
    }
}

// Round 3
// 677.128 us; speedup vs baseline: 2.2272x; 2.2272x over previous
//
#include <hip/hip_runtime.h>
#include <math.h>

#define N_NODES 100000
#define NE 1000000
#define D_NODE 64
#define D_EDGE 32
#define HID 64
#define H2C 32
#define D_IN 160   // 2*D_NODE + D_EDGE
#define EPS_LOGIT 1e-3f

// ws layout: [0..3] int counter + pad; list of flagged edge ids from int #4.

__global__ void zero_counter_kernel(int* __restrict__ c) {
    if (blockIdx.x == 0 && threadIdx.x == 0) c[0] = 0;
}

__global__ __launch_bounds__(256, 4) void edge_mlp_f32_kernel(
    const float* __restrict__ nf,   // [N_NODES][D_NODE]
    const int*   __restrict__ ei,   // [2][E] int32 or int64-as-dwords
    const float* __restrict__ ef,   // [E][D_EDGE]
    const float* __restrict__ W1, const float* __restrict__ b1,
    const float* __restrict__ W2, const float* __restrict__ b2,
    const float* __restrict__ W3, const float* __restrict__ b3,
    int* __restrict__ counter, int* __restrict__ list, int cap,
    float* __restrict__ out)        // [2E]: scores then mask
{
    const int e = blockIdx.x * blockDim.x + threadIdx.x;
    if (e >= NE) return;

    // int64 detection: odd dwords of small int64 values are 0. Uniform.
    const int is64 = (ei[1] == 0) & (ei[3] == 0) & (ei[5] == 0) & (ei[7] == 0);
    int si, ti;
    if (is64) {
        si = ei[2 * (size_t)e];
        ti = ei[2 * ((size_t)NE + e)];
    } else {
        si = ei[e];
        ti = ei[NE + e];
    }

    const float* __restrict__ srcp = nf + (size_t)si * D_NODE;
    const float* __restrict__ tgtp = nf + (size_t)ti * D_NODE;
    const float* __restrict__ efp  = ef + (size_t)e  * D_EDGE;

    // ---- Layer 1: acc[j] = b1[j] + sum_k combined[k]*W1[j][k] ----
    float acc[HID];
    #pragma unroll
    for (int j = 0; j < HID; ++j) acc[j] = b1[j];

    #pragma unroll 1
    for (int kc = 0; kc < D_IN / 16; ++kc) {
        const float* base = (kc < 4) ? (srcp + kc * 16)
                          : (kc < 8) ? (tgtp + (kc - 4) * 16)
                                     : (efp  + (kc - 8) * 16);
        float c[16];
        #pragma unroll
        for (int q = 0; q < 4; ++q) {
            const float4 v = *reinterpret_cast<const float4*>(base + q * 4);
            c[q * 4 + 0] = v.x; c[q * 4 + 1] = v.y;
            c[q * 4 + 2] = v.z; c[q * 4 + 3] = v.w;
        }
        #pragma unroll
        for (int j = 0; j < HID; ++j) {
            #pragma unroll
            for (int q = 0; q < 16; ++q)
                acc[j] = fmaf(c[q], W1[j * D_IN + kc * 16 + q], acc[j]);
        }
    }
    #pragma unroll
    for (int j = 0; j < HID; ++j) acc[j] = fmaxf(acc[j], 0.0f);

    // ---- Layers 2+3 fused ----
    float logit = b3[0];
    #pragma unroll 1
    for (int jj = 0; jj < H2C; ++jj) {
        float h = b2[jj];
        #pragma unroll
        for (int j = 0; j < HID; ++j)
            h = fmaf(acc[j], W2[jj * HID + j], h);
        h = fmaxf(h, 0.0f);
        logit = fmaf(h, W3[jj], logit);
    }

    const float score = 1.0f / (1.0f + expf(-logit));
    out[e] = score;
    out[(size_t)NE + e] = (score >= 0.5f) ? 1.0f : 0.0f;

    // Flag knife-edge edges for f64 fixup.
    if (fabsf(logit) < EPS_LOGIT) {
        const int idx = atomicAdd(counter, 1);
        if (idx < cap) list[idx] = e;
    }
}

// f64 recompute for flagged edges (tiny count; perf-irrelevant, reg-heavy OK).
__global__ __launch_bounds__(256, 1) void fixup_f64_kernel(
    const float* __restrict__ nf,
    const int*   __restrict__ ei,
    const float* __restrict__ ef,
    const float* __restrict__ W1, const float* __restrict__ b1,
    const float* __restrict__ W2, const float* __restrict__ b2,
    const float* __restrict__ W3, const float* __restrict__ b3,
    const int* __restrict__ counter, const int* __restrict__ list, int cap,
    float* __restrict__ out)
{
    const int n = min(counter[0], cap);
    const int is64 = (ei[1] == 0) & (ei[3] == 0) & (ei[5] == 0) & (ei[7] == 0);

    for (int i = blockIdx.x * blockDim.x + threadIdx.x; i < n;
         i += gridDim.x * blockDim.x) {
        const int e = list[i];
        int si, ti;
        if (is64) {
            si = ei[2 * (size_t)e];
            ti = ei[2 * ((size_t)NE + e)];
        } else {
            si = ei[e];
            ti = ei[NE + e];
        }
        const float* __restrict__ srcp = nf + (size_t)si * D_NODE;
        const float* __restrict__ tgtp = nf + (size_t)ti * D_NODE;
        const float* __restrict__ efp  = ef + (size_t)e  * D_EDGE;

        double acc[HID];
        #pragma unroll
        for (int j = 0; j < HID; ++j) acc[j] = (double)b1[j];

        #pragma unroll 1
        for (int kc = 0; kc < D_IN / 16; ++kc) {
            const float* base = (kc < 4) ? (srcp + kc * 16)
                              : (kc < 8) ? (tgtp + (kc - 4) * 16)
                                         : (efp  + (kc - 8) * 16);
            double cd[16];
            #pragma unroll
            for (int q = 0; q < 4; ++q) {
                const float4 v = *reinterpret_cast<const float4*>(base + q * 4);
                cd[q * 4 + 0] = (double)v.x; cd[q * 4 + 1] = (double)v.y;
                cd[q * 4 + 2] = (double)v.z; cd[q * 4 + 3] = (double)v.w;
            }
            #pragma unroll
            for (int j = 0; j < HID; ++j) {
                #pragma unroll
                for (int q = 0; q < 16; ++q)
                    acc[j] = fma(cd[q], (double)W1[j * D_IN + kc * 16 + q], acc[j]);
            }
        }
        #pragma unroll
        for (int j = 0; j < HID; ++j) acc[j] = fmax(acc[j], 0.0);

        double logit = (double)b3[0];
        #pragma unroll 1
        for (int jj = 0; jj < H2C; ++jj) {
            double h = (double)b2[jj];
            #pragma unroll
            for (int j = 0; j < HID; ++j)
                h = fma(acc[j], (double)W2[jj * HID + j], h);
            h = fmax(h, 0.0);
            logit = fma(h, (double)W3[jj], logit);
        }

        const float score_f = (float)(1.0 / (1.0 + exp(-logit)));
        out[e] = score_f;
        out[(size_t)NE + e] = (score_f >= 0.5f) ? 1.0f : 0.0f;
    }
}

extern "C" void kernel_launch(void* const* d_in, const int* in_sizes, int n_in,
                              void* d_out, int out_size, void* d_ws, size_t ws_size,
                              hipStream_t stream) {
    const float* nf = (const float*)d_in[0];
    const int*   ei = (const int*)  d_in[1];
    const float* ef = (const float*)d_in[2];
    const float* W1 = (const float*)d_in[3];
    const float* b1 = (const float*)d_in[4];
    const float* W2 = (const float*)d_in[5];
    const float* b2 = (const float*)d_in[6];
    const float* W3 = (const float*)d_in[7];
    const float* b3 = (const float*)d_in[8];
    float* out = (float*)d_out;

    int* counter = (int*)d_ws;
    int* list = (int*)d_ws + 4;
    const long long cap_ll = ((long long)ws_size - 16) / 4;
    const int cap = (int)((cap_ll < 0) ? 0 : (cap_ll > NE ? NE : cap_ll));

    hipLaunchKernelGGL(zero_counter_kernel, dim3(1), dim3(64), 0, stream, counter);

    const int block = 256;
    const int grid = (NE + block - 1) / block;
    hipLaunchKernelGGL(edge_mlp_f32_kernel, dim3(grid), dim3(block), 0, stream,
                       nf, ei, ef, W1, b1, W2, b2, W3, b3,
                       counter, list, cap, out);

    hipLaunchKernelGGL(fixup_f64_kernel, dim3(64), dim3(block), 0, stream,
                       nf, ei, ef, W1, b1, W2, b2, W3, b3,
                       counter, list, cap, out);
}

// Round 4
// 518.216 us; speedup vs baseline: 2.9102x; 1.3067x over previous
//
#include <hip/hip_runtime.h>
#include <math.h>

#define NE 1000000
#define D_NODE 64
#define D_EDGE 32
#define HID 64
#define H2C 32
#define D_IN 160
#define NT1 4   // layer-1 N-tiles (64 hidden / 16)
#define KT1 5   // layer-1 K-tiles (160 / 32)
#define NT2 2   // layer-2 N-tiles (32 / 16)
#define KT2 2   // layer-2 K-tiles (64 / 32)
#define EPS_LOGIT 1e-3f

typedef __attribute__((ext_vector_type(8))) short short8;   // 8 bf16
typedef __attribute__((ext_vector_type(4))) float f32x4;

// ws byte layout: [0,16) flag counter; then packed W1/W2 bf16x2 fragments; then flag list
#define WS_W1_OFF 16
#define FRAG_BYTES 2048                                  // 64 lanes * (8 hi + 8 lo) bf16
#define WS_W2_OFF (WS_W1_OFF + NT1*KT1*FRAG_BYTES)       // 16 + 40960
#define WS_LIST_OFF (WS_W2_OFF + NT2*KT2*FRAG_BYTES)     // + 8192 = 49168
#define WS_MAIN_MIN (WS_LIST_OFF + 65536)                // list cap >= 16K edges

__device__ __forceinline__ unsigned short bf16_rne(float x) {
    unsigned int u = __float_as_uint(x);
    u += 0x7fffu + ((u >> 16) & 1u);
    return (unsigned short)(u >> 16);
}
__device__ __forceinline__ float bf16_tof(unsigned short h) {
    return __uint_as_float(((unsigned int)h) << 16);
}
__device__ __forceinline__ void split8(const float* xs, short8& hi, short8& lo) {
    #pragma unroll
    for (int i = 0; i < 8; ++i) {
        unsigned short h = bf16_rne(xs[i]);
        float fh = bf16_tof(h);
        unsigned short l = bf16_rne(xs[i] - fh);
        hi[i] = (short)h;
        lo[i] = (short)l;
    }
}

// Pack W1/W2 into per-lane MFMA B-fragment order (hi8|lo8 per lane), zero counter.
__global__ void prep_pack_kernel(const float* __restrict__ W1,
                                 const float* __restrict__ W2,
                                 unsigned char* __restrict__ ws) {
    const int t = blockIdx.x * blockDim.x + threadIdx.x;
    if (t == 0) *(int*)ws = 0;
    unsigned short* w1p = (unsigned short*)(ws + WS_W1_OFF);
    unsigned short* w2p = (unsigned short*)(ws + WS_W2_OFF);
    const int total1 = NT1 * KT1 * 64;
    const int total2 = NT2 * KT2 * 64;
    for (int task = t; task < total1 + total2; task += gridDim.x * blockDim.x) {
        const int isW2 = task >= total1;
        const int tt = isW2 ? task - total1 : task;
        const int f = tt >> 6, l = tt & 63;
        const int nn = isW2 ? f / KT2 : f / KT1;
        const int kk = isW2 ? f % KT2 : f % KT1;
        const int n = nn * 16 + (l & 15);
        const int kb = kk * 32 + (l >> 4) * 8;
        const float* Wp = isW2 ? (W2 + n * HID + kb) : (W1 + n * D_IN + kb);
        unsigned short* dst = (isW2 ? w2p : w1p) + ((size_t)f * 64 + l) * 16;
        #pragma unroll
        for (int i = 0; i < 8; ++i) {
            const float w = Wp[i];
            const unsigned short h = bf16_rne(w);
            dst[i] = h;
            dst[8 + i] = bf16_rne(w - bf16_tof(h));
        }
    }
}

__global__ __launch_bounds__(256) void edge_mlp_mfma_kernel(
    const float* __restrict__ nf, const int* __restrict__ ei,
    const float* __restrict__ ef,
    const float* __restrict__ b1, const float* __restrict__ b2,
    const float* __restrict__ W3, const float* __restrict__ b3,
    const unsigned short* __restrict__ w1p, const unsigned short* __restrict__ w2p,
    int* __restrict__ counter, int* __restrict__ list, int cap,
    float* __restrict__ out)
{
    __shared__ __attribute__((aligned(16))) float Hs[4][16][68];  // pad 64->68: <=2-way banks
    const int wave = threadIdx.x >> 6;
    const int lane = threadIdx.x & 63;
    const int l15 = lane & 15;
    const int kg = lane >> 4;

    const int is64 = (ei[1] == 0) & (ei[3] == 0) & (ei[5] == 0) & (ei[7] == 0);
    const long long e0 = (long long)blockIdx.x * 128 + wave * 32;  // 2 M-tiles of 16 edges

    const float* srcp[2]; const float* tgtp[2]; const float* efpp[2];
    #pragma unroll
    for (int t = 0; t < 2; ++t) {
        long long e = e0 + t * 16 + l15;
        if (e >= NE) e = NE - 1;  // tail clamp (writes masked later)
        int si, ti;
        if (is64) { si = ei[(size_t)(2 * e)]; ti = ei[(size_t)2 * (NE + e)]; }
        else      { si = ei[(size_t)e];       ti = ei[(size_t)(NE + e)]; }
        srcp[t] = nf + (size_t)si * D_NODE;
        tgtp[t] = nf + (size_t)ti * D_NODE;
        efpp[t] = ef + (size_t)e * D_EDGE;
    }

    const f32x4 zero4 = {0.f, 0.f, 0.f, 0.f};
    f32x4 acc1[2][NT1];
    #pragma unroll
    for (int t = 0; t < 2; ++t)
        #pragma unroll
        for (int nn = 0; nn < NT1; ++nn) acc1[t][nn] = zero4;

    // ---- Layer 1: X[32 edges x 160] @ W1^T via bf16x2 (hi,lo) 3-MFMA ----
    #pragma unroll
    for (int kk = 0; kk < KT1; ++kk) {
        short8 ahi[2], alo[2];
        #pragma unroll
        for (int t = 0; t < 2; ++t) {
            const float* base;
            if (kk == 0)      base = srcp[t] + kg * 8;
            else if (kk == 1) base = srcp[t] + 32 + kg * 8;
            else if (kk == 2) base = tgtp[t] + kg * 8;
            else if (kk == 3) base = tgtp[t] + 32 + kg * 8;
            else              base = efpp[t] + kg * 8;
            const float4 x0 = *(const float4*)base;
            const float4 x1 = *(const float4*)(base + 4);
            float xs[8] = {x0.x, x0.y, x0.z, x0.w, x1.x, x1.y, x1.z, x1.w};
            split8(xs, ahi[t], alo[t]);
        }
        #pragma unroll
        for (int nn = 0; nn < NT1; ++nn) {
            const unsigned short* fp = w1p + ((size_t)(nn * KT1 + kk) * 64 + lane) * 16;
            const short8 bhi = *(const short8*)fp;
            const short8 blo = *(const short8*)(fp + 8);
            #pragma unroll
            for (int t = 0; t < 2; ++t) {
                acc1[t][nn] = __builtin_amdgcn_mfma_f32_16x16x32_bf16(ahi[t], bhi, acc1[t][nn], 0, 0, 0);
                acc1[t][nn] = __builtin_amdgcn_mfma_f32_16x16x32_bf16(ahi[t], blo, acc1[t][nn], 0, 0, 0);
                acc1[t][nn] = __builtin_amdgcn_mfma_f32_16x16x32_bf16(alo[t], bhi, acc1[t][nn], 0, 0, 0);
            }
        }
    }

    float b1v[NT1];
    #pragma unroll
    for (int nn = 0; nn < NT1; ++nn) b1v[nn] = b1[nn * 16 + l15];
    const float b2a = b2[l15], b2b = b2[16 + l15];
    const float w3a = W3[l15], w3b = W3[16 + l15];
    const float b3s = b3[0];

    // ---- Per M-tile: LDS transpose -> layer 2 MFMA -> layer 3 in-register ----
    #pragma unroll
    for (int t = 0; t < 2; ++t) {
        #pragma unroll
        for (int nn = 0; nn < NT1; ++nn)
            #pragma unroll
            for (int r = 0; r < 4; ++r)
                Hs[wave][kg * 4 + r][nn * 16 + l15] = fmaxf(acc1[t][nn][r] + b1v[nn], 0.0f);
        asm volatile("s_waitcnt lgkmcnt(0)" ::: "memory");

        f32x4 acc2[NT2];
        acc2[0] = zero4; acc2[1] = zero4;
        #pragma unroll
        for (int kk = 0; kk < KT2; ++kk) {
            const float* hp = &Hs[wave][l15][kk * 32 + kg * 8];
            const float4 x0 = *(const float4*)hp;
            const float4 x1 = *(const float4*)(hp + 4);
            float xs[8] = {x0.x, x0.y, x0.z, x0.w, x1.x, x1.y, x1.z, x1.w};
            short8 a2hi, a2lo;
            split8(xs, a2hi, a2lo);
            #pragma unroll
            for (int nn = 0; nn < NT2; ++nn) {
                const unsigned short* fp = w2p + ((size_t)(nn * KT2 + kk) * 64 + lane) * 16;
                const short8 bhi = *(const short8*)fp;
                const short8 blo = *(const short8*)(fp + 8);
                acc2[nn] = __builtin_amdgcn_mfma_f32_16x16x32_bf16(a2hi, bhi, acc2[nn], 0, 0, 0);
                acc2[nn] = __builtin_amdgcn_mfma_f32_16x16x32_bf16(a2hi, blo, acc2[nn], 0, 0, 0);
                acc2[nn] = __builtin_amdgcn_mfma_f32_16x16x32_bf16(a2lo, bhi, acc2[nn], 0, 0, 0);
            }
        }
        asm volatile("s_waitcnt lgkmcnt(0)" ::: "memory");

        float vv[4];
        #pragma unroll
        for (int r = 0; r < 4; ++r) {
            float x = fmaxf(acc2[0][r] + b2a, 0.f) * w3a + fmaxf(acc2[1][r] + b2b, 0.f) * w3b;
            #pragma unroll
            for (int off = 1; off < 16; off <<= 1) x += __shfl_xor(x, off, 16);
            vv[r] = x + b3s;
        }
        if (l15 < 4) {
            const float lg = (l15 == 0) ? vv[0] : (l15 == 1) ? vv[1] : (l15 == 2) ? vv[2] : vv[3];
            const long long e = e0 + t * 16 + kg * 4 + l15;
            if (e < NE) {
                const float sc = 1.0f / (1.0f + expf(-lg));
                out[e] = sc;
                out[NE + e] = (sc >= 0.5f) ? 1.0f : 0.0f;
                if (fabsf(lg) < EPS_LOGIT) {
                    const int idx = atomicAdd(counter, 1);
                    if (idx < cap) list[idx] = (int)e;
                }
            }
        }
    }
}

// Wave-per-edge f64 recompute: lane j owns hidden unit j (low latency for the tail).
__global__ __launch_bounds__(256) void fixup_wave_f64_kernel(
    const float* __restrict__ nf, const int* __restrict__ ei,
    const float* __restrict__ ef,
    const float* __restrict__ W1, const float* __restrict__ b1,
    const float* __restrict__ W2, const float* __restrict__ b2,
    const float* __restrict__ W3, const float* __restrict__ b3,
    const int* __restrict__ counter, const int* __restrict__ list, int cap,
    float* __restrict__ out)
{
    __shared__ double fh[4][HID];
    const int wave = threadIdx.x >> 6, lane = threadIdx.x & 63;
    const int nwaves = (gridDim.x * blockDim.x) >> 6;
    const int wid = (blockIdx.x * blockDim.x + threadIdx.x) >> 6;
    int n = counter[0]; if (n > cap) n = cap;
    const int is64 = (ei[1] == 0) & (ei[3] == 0) & (ei[5] == 0) & (ei[7] == 0);

    for (int i = wid; i < n; i += nwaves) {
        const int e = list[i];
        int si, ti;
        if (is64) { si = ei[(size_t)2 * e]; ti = ei[(size_t)2 * (NE + (long long)e)]; }
        else      { si = ei[e];             ti = ei[NE + (size_t)e]; }
        const float* sp = nf + (size_t)si * D_NODE;
        const float* tp = nf + (size_t)ti * D_NODE;
        const float* ep = ef + (size_t)e * D_EDGE;

        double a = (double)b1[lane];
        for (int k = 0; k < 64; ++k) a = fma((double)sp[k], (double)W1[lane * D_IN + k], a);
        for (int k = 0; k < 64; ++k) a = fma((double)tp[k], (double)W1[lane * D_IN + 64 + k], a);
        for (int k = 0; k < 32; ++k) a = fma((double)ep[k], (double)W1[lane * D_IN + 128 + k], a);
        fh[wave][lane] = fmax(a, 0.0);
        asm volatile("s_waitcnt lgkmcnt(0)" ::: "memory");

        double tsum = 0.0;
        if (lane < H2C) {
            double h = (double)b2[lane];
            for (int j = 0; j < HID; ++j) h = fma(fh[wave][j], (double)W2[lane * HID + j], h);
            tsum = fmax(h, 0.0) * (double)W3[lane];
        }
        #pragma unroll
        for (int off = 1; off < 32; off <<= 1) tsum += __shfl_xor(tsum, off, 32);
        if (lane == 0) {
            const double logit = tsum + (double)b3[0];
            const float sc = (float)(1.0 / (1.0 + exp(-logit)));
            out[e] = sc;
            out[NE + (size_t)e] = (sc >= 0.5f) ? 1.0f : 0.0f;
        }
        asm volatile("s_waitcnt lgkmcnt(0)" ::: "memory");
    }
}

// ---------- Fallback (ws too small): round-3 proven f32 VALU path ----------
__global__ void zero_counter_kernel(int* __restrict__ c) {
    if (blockIdx.x == 0 && threadIdx.x == 0) c[0] = 0;
}

__global__ __launch_bounds__(256, 4) void edge_mlp_f32_kernel(
    const float* __restrict__ nf, const int* __restrict__ ei,
    const float* __restrict__ ef,
    const float* __restrict__ W1, const float* __restrict__ b1,
    const float* __restrict__ W2, const float* __restrict__ b2,
    const float* __restrict__ W3, const float* __restrict__ b3,
    int* __restrict__ counter, int* __restrict__ list, int cap,
    float* __restrict__ out)
{
    const int e = blockIdx.x * blockDim.x + threadIdx.x;
    if (e >= NE) return;
    const int is64 = (ei[1] == 0) & (ei[3] == 0) & (ei[5] == 0) & (ei[7] == 0);
    int si, ti;
    if (is64) { si = ei[2 * (size_t)e]; ti = ei[2 * ((size_t)NE + e)]; }
    else      { si = ei[e];             ti = ei[NE + e]; }
    const float* srcp = nf + (size_t)si * D_NODE;
    const float* tgtp = nf + (size_t)ti * D_NODE;
    const float* efp  = ef + (size_t)e  * D_EDGE;

    float acc[HID];
    #pragma unroll
    for (int j = 0; j < HID; ++j) acc[j] = b1[j];
    #pragma unroll 1
    for (int kc = 0; kc < D_IN / 16; ++kc) {
        const float* base = (kc < 4) ? (srcp + kc * 16)
                          : (kc < 8) ? (tgtp + (kc - 4) * 16)
                                     : (efp  + (kc - 8) * 16);
        float c[16];
        #pragma unroll
        for (int q = 0; q < 4; ++q) {
            const float4 v = *reinterpret_cast<const float4*>(base + q * 4);
            c[q * 4 + 0] = v.x; c[q * 4 + 1] = v.y; c[q * 4 + 2] = v.z; c[q * 4 + 3] = v.w;
        }
        #pragma unroll
        for (int j = 0; j < HID; ++j)
            #pragma unroll
            for (int q = 0; q < 16; ++q)
                acc[j] = fmaf(c[q], W1[j * D_IN + kc * 16 + q], acc[j]);
    }
    #pragma unroll
    for (int j = 0; j < HID; ++j) acc[j] = fmaxf(acc[j], 0.0f);

    float logit = b3[0];
    #pragma unroll 1
    for (int jj = 0; jj < H2C; ++jj) {
        float h = b2[jj];
        #pragma unroll
        for (int j = 0; j < HID; ++j) h = fmaf(acc[j], W2[jj * HID + j], h);
        logit = fmaf(fmaxf(h, 0.0f), W3[jj], logit);
    }
    const float score = 1.0f / (1.0f + expf(-logit));
    out[e] = score;
    out[(size_t)NE + e] = (score >= 0.5f) ? 1.0f : 0.0f;
    if (fabsf(logit) < EPS_LOGIT) {
        const int idx = atomicAdd(counter, 1);
        if (idx < cap) list[idx] = e;
    }
}

extern "C" void kernel_launch(void* const* d_in, const int* in_sizes, int n_in,
                              void* d_out, int out_size, void* d_ws, size_t ws_size,
                              hipStream_t stream) {
    const float* nf = (const float*)d_in[0];
    const int*   ei = (const int*)  d_in[1];
    const float* ef = (const float*)d_in[2];
    const float* W1 = (const float*)d_in[3];
    const float* b1 = (const float*)d_in[4];
    const float* W2 = (const float*)d_in[5];
    const float* b2 = (const float*)d_in[6];
    const float* W3 = (const float*)d_in[7];
    const float* b3 = (const float*)d_in[8];
    float* out = (float*)d_out;
    unsigned char* ws = (unsigned char*)d_ws;
    int* counter = (int*)ws;

    if (ws_size >= (size_t)WS_MAIN_MIN) {
        long long cap_ll = ((long long)ws_size - WS_LIST_OFF) / 4;
        const int cap = (int)(cap_ll > NE ? NE : cap_ll);
        int* list = (int*)(ws + WS_LIST_OFF);
        hipLaunchKernelGGL(prep_pack_kernel, dim3(6), dim3(256), 0, stream, W1, W2, ws);
        const int grid = (NE + 127) / 128;
        hipLaunchKernelGGL(edge_mlp_mfma_kernel, dim3(grid), dim3(256), 0, stream,
                           nf, ei, ef, b1, b2, W3, b3,
                           (const unsigned short*)(ws + WS_W1_OFF),
                           (const unsigned short*)(ws + WS_W2_OFF),
                           counter, list, cap, out);
        hipLaunchKernelGGL(fixup_wave_f64_kernel, dim3(256), dim3(256), 0, stream,
                           nf, ei, ef, W1, b1, W2, b2, W3, b3,
                           counter, list, cap, out);
    } else {
        long long cap_ll = ((long long)ws_size - 16) / 4;
        const int cap = (int)(cap_ll < 0 ? 0 : (cap_ll > NE ? NE : cap_ll));
        int* list = (int*)(ws + 16);
        hipLaunchKernelGGL(zero_counter_kernel, dim3(1), dim3(64), 0, stream, counter);
        hipLaunchKernelGGL(edge_mlp_f32_kernel, dim3((NE + 255) / 256), dim3(256), 0, stream,
                           nf, ei, ef, W1, b1, W2, b2, W3, b3, counter, list, cap, out);
        hipLaunchKernelGGL(fixup_wave_f64_kernel, dim3(256), dim3(256), 0, stream,
                           nf, ei, ef, W1, b1, W2, b2, W3, b3, counter, list, cap, out);
    }
}